// Round 2
// baseline (162.767 us; speedup 1.0000x reference)
//
#include <hip/hip_runtime.h>
#include <hip/hip_bf16.h>

constexpr int BB = 4;
constexpr int SS = 1024;
constexpr int HH = 16;
constexpr int DH = 64;
constexpr int DM = 1024;

using f32x4 = __attribute__((ext_vector_type(4))) float;
using s16x8 = __attribute__((ext_vector_type(8))) short;

__device__ __forceinline__ f32x4 mfma_bf16(s16x8 a, s16x8 b, f32x4 c) {
    return __builtin_amdgcn_mfma_f32_16x16x32_bf16(a, b, c, 0, 0, 0);
}

// ---------------- QKV projection ----------------
// grid 512 = (B*H) * (S/128); block 192 = 3 waves.
// thread t: m = t/64 (0=q,1=k,2=v), e = t%64 -> owns output column e of matrix m.
// W row W[h][e][0..63] held in 64 VGPRs; x tile [128][64] in LDS (broadcast reads).
__global__ __launch_bounds__(192) void qkv_proj_kernel(
    const float* __restrict__ x,
    const float* __restrict__ Wq, const float* __restrict__ Wk, const float* __restrict__ Wv,
    const float* __restrict__ bq, const float* __restrict__ bk, const float* __restrict__ bv,
    __hip_bfloat16* __restrict__ q_ws, __hip_bfloat16* __restrict__ k_ws,
    __hip_bfloat16* __restrict__ v_ws)
{
    const int bid  = blockIdx.x;
    const int tile = bid & 7;          // s-tile of 128 rows
    const int pair = bid >> 3;         // b*H + h
    const int b = pair >> 4, h = pair & 15;
    const int t = threadIdx.x;
    const int m = t >> 6;
    const int e = t & 63;

    __shared__ float xs[128][64];

    const float* Wm = (m == 0) ? Wq : (m == 1) ? Wk : Wv;
    const float* bm = (m == 0) ? bq : (m == 1) ? bk : bv;

    float wreg[64];
    const float* wrow = Wm + ((size_t)h * DH + e) * DH;
    #pragma unroll
    for (int i = 0; i < 16; ++i) {
        float4 w4 = reinterpret_cast<const float4*>(wrow)[i];
        wreg[4*i+0] = w4.x; wreg[4*i+1] = w4.y; wreg[4*i+2] = w4.z; wreg[4*i+3] = w4.w;
    }
    const float bias = bm[h * DH + e];

    const int s0 = tile * 128;
    for (int i = t; i < 128 * 16; i += 192) {
        int r = i >> 4, c = i & 15;
        reinterpret_cast<float4*>(&xs[r][0])[c] =
            reinterpret_cast<const float4*>(x + (size_t)(b * SS + s0 + r) * DM + h * DH)[c];
    }
    __syncthreads();

    const size_t qk_base = ((size_t)pair * SS + s0) * DH + e;   // [B,H,S,64]
    const size_t v_base  = ((size_t)pair * DH + e) * SS + s0;   // [B,H,64,S] (transposed)
    for (int r = 0; r < 128; ++r) {
        float acc = bias;
        #pragma unroll
        for (int dv = 0; dv < 16; ++dv) {
            float4 xv = reinterpret_cast<const float4*>(&xs[r][0])[dv];
            acc = fmaf(xv.x, wreg[4*dv+0], acc);
            acc = fmaf(xv.y, wreg[4*dv+1], acc);
            acc = fmaf(xv.z, wreg[4*dv+2], acc);
            acc = fmaf(xv.w, wreg[4*dv+3], acc);
        }
        __hip_bfloat16 hb = __float2bfloat16(acc);
        if      (m == 0) q_ws[qk_base + (size_t)r * DH] = hb;
        else if (m == 1) k_ws[qk_base + (size_t)r * DH] = hb;
        else             v_ws[v_base + r] = hb;
    }
}

// ---------------- Flash attention ----------------
// grid 1024 = (B*H) * (S/64); block 256 = 4 waves; wave w owns q-rows [w*16, w*16+16).
// C/D layout of mfma_f32_16x16x32_bf16: col = lane&15, row = (lane>>4)*4 + reg.
// A/B fragment: lane holds row (lane&15), k = (lane>>4)*8 + j (row-major contiguous 8).
__global__ __launch_bounds__(256) void attn_kernel(
    const __hip_bfloat16* __restrict__ q_ws,
    const __hip_bfloat16* __restrict__ k_ws,
    const __hip_bfloat16* __restrict__ v_ws,
    float* __restrict__ out)
{
    const int bid  = blockIdx.x;
    const int qt   = bid & 15;
    const int pair = bid >> 4;
    const int b = pair >> 4, h = pair & 15;
    const int t = threadIdx.x;
    const int w = t >> 6, l = t & 63;
    const int lr = l & 15, lg = l >> 4;

    __shared__ __hip_bfloat16 Ks[32][64];       // K tile, row-major [k][d]
    __shared__ __hip_bfloat16 Vt[64][32];       // V tile transposed [d][k]
    __shared__ __hip_bfloat16 Pl[4][16][32];    // per-wave P round-trip

    // Q fragments (held whole loop): rows qt*64 + w*16 + lr
    const __hip_bfloat16* qrow =
        q_ws + ((size_t)pair * SS + qt * 64 + w * 16 + lr) * DH;
    const s16x8 qf0 = *reinterpret_cast<const s16x8*>(qrow + lg * 8);
    const s16x8 qf1 = *reinterpret_cast<const s16x8*>(qrow + 32 + lg * 8);

    f32x4 o[4];
    #pragma unroll
    for (int d = 0; d < 4; ++d) o[d] = f32x4{0.f, 0.f, 0.f, 0.f};
    float mrow[4] = {-1e30f, -1e30f, -1e30f, -1e30f};
    float lrow[4] = {0.f, 0.f, 0.f, 0.f};

    const int kr = t >> 3, kc = t & 7;          // K staging: 32 rows x 8 chunks
    const int vd = t >> 2, vc = t & 3;          // V staging: 64 rows x 4 chunks
    const __hip_bfloat16* kbase = k_ws + ((size_t)pair * SS + kr) * DH + kc * 8;
    const __hip_bfloat16* vbase = v_ws + ((size_t)pair * DH + vd) * SS + vc * 8;

    for (int kt = 0; kt < SS / 32; ++kt) {
        *reinterpret_cast<s16x8*>(&Ks[kr][kc * 8]) =
            *reinterpret_cast<const s16x8*>(kbase + (size_t)kt * 32 * DH);
        *reinterpret_cast<s16x8*>(&Vt[vd][vc * 8]) =
            *reinterpret_cast<const s16x8*>(vbase + kt * 32);
        __syncthreads();

        // S = Q.K^T for two 16-col key blocks
        f32x4 sfr[2];
        #pragma unroll
        for (int kb = 0; kb < 2; ++kb) {
            s16x8 kf0 = *reinterpret_cast<const s16x8*>(&Ks[kb * 16 + lr][lg * 8]);
            s16x8 kf1 = *reinterpret_cast<const s16x8*>(&Ks[kb * 16 + lr][32 + lg * 8]);
            f32x4 acc = f32x4{0.f, 0.f, 0.f, 0.f};
            acc = mfma_bf16(qf0, kf0, acc);
            acc = mfma_bf16(qf1, kf1, acc);
            sfr[kb] = acc;
        }

        // online softmax, per accumulator reg (= q-row)
        #pragma unroll
        for (int r = 0; r < 4; ++r) {
            float s0 = sfr[0][r] * 0.125f;
            float s1 = sfr[1][r] * 0.125f;
            float mx = fmaxf(s0, s1);
            mx = fmaxf(mx, __shfl_xor(mx, 1));
            mx = fmaxf(mx, __shfl_xor(mx, 2));
            mx = fmaxf(mx, __shfl_xor(mx, 4));
            mx = fmaxf(mx, __shfl_xor(mx, 8));
            float mnew  = fmaxf(mrow[r], mx);
            float alpha = __expf(mrow[r] - mnew);
            float p0 = __expf(s0 - mnew);
            float p1 = __expf(s1 - mnew);
            float rs = p0 + p1;
            rs += __shfl_xor(rs, 1);
            rs += __shfl_xor(rs, 2);
            rs += __shfl_xor(rs, 4);
            rs += __shfl_xor(rs, 8);
            lrow[r] = lrow[r] * alpha + rs;
            mrow[r] = mnew;
            #pragma unroll
            for (int d = 0; d < 4; ++d) o[d][r] *= alpha;
            const int qr = lg * 4 + r;
            Pl[w][qr][lr]      = __float2bfloat16(p0);
            Pl[w][qr][16 + lr] = __float2bfloat16(p1);
        }

        // O += P.V   (A = P from wave-private LDS; B = V via transposed tile)
        s16x8 pf = *reinterpret_cast<const s16x8*>(&Pl[w][lr][lg * 8]);
        #pragma unroll
        for (int d = 0; d < 4; ++d) {
            s16x8 vf = *reinterpret_cast<const s16x8*>(&Vt[d * 16 + lr][lg * 8]);
            o[d] = mfma_bf16(pf, vf, o[d]);
        }
        __syncthreads();
    }

    #pragma unroll
    for (int r = 0; r < 4; ++r) {
        const int srow = qt * 64 + w * 16 + lg * 4 + r;
        const float inv = 1.0f / lrow[r];
        #pragma unroll
        for (int d = 0; d < 4; ++d) {
            out[((size_t)b * SS + srow) * DM + h * DH + d * 16 + lr] = o[d][r] * inv;
        }
    }
}

extern "C" void kernel_launch(void* const* d_in, const int* in_sizes, int n_in,
                              void* d_out, int out_size, void* d_ws, size_t ws_size,
                              hipStream_t stream) {
    const float* x  = (const float*)d_in[0];
    const float* Wq = (const float*)d_in[1];
    const float* Wk = (const float*)d_in[2];
    const float* Wv = (const float*)d_in[3];
    const float* bq = (const float*)d_in[4];
    const float* bk = (const float*)d_in[5];
    const float* bv = (const float*)d_in[6];
    float* out = (float*)d_out;

    __hip_bfloat16* q_ws = (__hip_bfloat16*)d_ws;
    __hip_bfloat16* k_ws = q_ws + (size_t)BB * HH * SS * DH;
    __hip_bfloat16* v_ws = k_ws + (size_t)BB * HH * SS * DH;

    qkv_proj_kernel<<<dim3(BB * HH * (SS / 128)), dim3(192), 0, stream>>>(
        x, Wq, Wk, Wv, bq, bk, bv, q_ws, k_ws, v_ws);
    attn_kernel<<<dim3(BB * HH * (SS / 64)), dim3(256), 0, stream>>>(
        q_ws, k_ws, v_ws, out);
}

// Round 4
// 95.355 us; speedup vs baseline: 1.7070x; 1.7070x over previous
//
#include <hip/hip_runtime.h>
#include <hip/hip_bf16.h>

constexpr int BB = 4;
constexpr int SS = 1024;
constexpr int HH = 16;
constexpr int DH = 64;
constexpr int DM = 1024;

using f32x16 = __attribute__((ext_vector_type(16))) float;
using s16x8  = __attribute__((ext_vector_type(8))) short;

__device__ __forceinline__ f32x16 mfma32(s16x8 a, s16x8 b, f32x16 c) {
    return __builtin_amdgcn_mfma_f32_32x32x16_bf16(a, b, c, 0, 0, 0);
}

__device__ __forceinline__ unsigned short bf16bits(float x) {
    union { __hip_bfloat16 h; unsigned short s; } cv;
    cv.h = __float2bfloat16(x);
    return cv.s;
}
__device__ __forceinline__ unsigned pk_bf16(float lo, float hi) {
    return (unsigned)bf16bits(lo) | ((unsigned)bf16bits(hi) << 16);
}

__device__ __forceinline__ float fast_exp2(float x) {
#if __has_builtin(__builtin_amdgcn_exp2f)
    return __builtin_amdgcn_exp2f(x);
#else
    return __expf(x * 0.6931471805599453f);
#endif
}

// ---------------- QKV projection ----------------
// grid 512 = (B*H)*(S/128); block 192 = 3 waves. m = t/64 (0=q,1=k,2=v), e = t%64.
// V is transposed to [B,H,64,S] THROUGH a swizzled LDS tile so global writes coalesce.
__global__ __launch_bounds__(192) void qkv_proj_kernel(
    const float* __restrict__ x,
    const float* __restrict__ Wq, const float* __restrict__ Wk, const float* __restrict__ Wv,
    const float* __restrict__ bq, const float* __restrict__ bk, const float* __restrict__ bv,
    __hip_bfloat16* __restrict__ q_ws, __hip_bfloat16* __restrict__ k_ws,
    __hip_bfloat16* __restrict__ v_ws)
{
    const int bid  = blockIdx.x;
    const int tile = bid & 7;
    const int pair = bid >> 3;
    const int b = pair >> 4, h = pair & 15;
    const int t = threadIdx.x;
    const int m = t >> 6;
    const int e = t & 63;

    __shared__ float xs[128][64];
    __shared__ __align__(16) char vt[64 * 256];   // [64 d][128 s] bf16, XOR-swizzled rows

    const float* Wm = (m == 0) ? Wq : (m == 1) ? Wk : Wv;
    const float* bm = (m == 0) ? bq : (m == 1) ? bk : bv;

    float wreg[64];
    const float* wrow = Wm + ((size_t)h * DH + e) * DH;
    #pragma unroll
    for (int i = 0; i < 16; ++i) {
        float4 w4 = reinterpret_cast<const float4*>(wrow)[i];
        wreg[4*i+0] = w4.x; wreg[4*i+1] = w4.y; wreg[4*i+2] = w4.z; wreg[4*i+3] = w4.w;
    }
    const float bias = bm[h * DH + e];

    const int s0 = tile * 128;
    for (int i = t; i < 128 * 16; i += 192) {
        int r = i >> 4, c = i & 15;
        reinterpret_cast<float4*>(&xs[r][0])[c] =
            reinterpret_cast<const float4*>(x + (size_t)(b * SS + s0 + r) * DM + h * DH)[c];
    }
    __syncthreads();

    const size_t qk_base = ((size_t)pair * SS + s0) * DH + e;   // [B,H,S,64]
    for (int r0 = 0; r0 < 16; ++r0) {
        s16x8 vv;
        #pragma unroll
        for (int rr = 0; rr < 8; ++rr) {
            const int r = r0 * 8 + rr;
            float acc = bias;
            #pragma unroll
            for (int dv = 0; dv < 16; ++dv) {
                float4 xv = reinterpret_cast<const float4*>(&xs[r][0])[dv];
                acc = fmaf(xv.x, wreg[4*dv+0], acc);
                acc = fmaf(xv.y, wreg[4*dv+1], acc);
                acc = fmaf(xv.z, wreg[4*dv+2], acc);
                acc = fmaf(xv.w, wreg[4*dv+3], acc);
            }
            union { __hip_bfloat16 hb; short sb; } cv;
            cv.hb = __float2bfloat16(acc);
            if      (m == 0) q_ws[qk_base + (size_t)r * DH] = cv.hb;
            else if (m == 1) k_ws[qk_base + (size_t)r * DH] = cv.hb;
            else             vv[rr] = cv.sb;
        }
        if (m == 2) {
            const int byte = e * 256 + ((r0 ^ (e & 15)) << 4);
            *reinterpret_cast<s16x8*>(vt + byte) = vv;
        }
    }
    __syncthreads();
    for (int i = t; i < 1024; i += 192) {
        const int row = i >> 4, cc = i & 15;
        const int byte = row * 256 + ((cc ^ (row & 15)) << 4);
        s16x8 val = *reinterpret_cast<const s16x8*>(vt + byte);
        *reinterpret_cast<s16x8*>(v_ws + ((size_t)pair * DH + row) * SS + s0 + cc * 8) = val;
    }
}

// ---------------- Flash attention (32x32 swapped-QK^T, in-register softmax) ----------------
// grid 512 = 64 pairs x 8 q-tiles (XCD-swizzled); block 256 = 4 waves x 32 q-rows.
// Swapped QK^T: sc = mfma(A=K, B=Q^T) -> C col = lane&31 = QUERY; lane holds 32 key-scores
// for its query: key(r,hi) = (r&3)+8*(r>>2)+4*hi (+32 per group).
// P half-exchange done with __shfl_xor(.,32)+select (semantics-safe; permlane A/B later).
// K/V LDS tiles [64][64] bf16 row-major, byte ^= (row&7)<<4 swizzle (conflict-free-ish b128).
__global__ __launch_bounds__(256) void attn_kernel(
    const __hip_bfloat16* __restrict__ q_ws,
    const __hip_bfloat16* __restrict__ k_ws,
    const __hip_bfloat16* __restrict__ v_ws,
    float* __restrict__ out)
{
    const int bid  = blockIdx.x;
    const int lbid = (bid & 7) * 64 + (bid >> 3);   // XCD-aware swizzle (512 % 8 == 0)
    const int qt   = lbid & 7;
    const int pair = lbid >> 3;
    const int b = pair >> 4, h = pair & 15;
    const int t = threadIdx.x;
    const int w = t >> 6, l = t & 63;
    const int lq = l & 31, hi = l >> 5;

    __shared__ __align__(16) char Kl[8192];
    __shared__ __align__(16) char Vl[8192];

    // Q fragments (B-operand): lane holds Q[q=lq][16*s5 + 8*hi + 0..7]
    const __hip_bfloat16* qp = q_ws + ((size_t)pair * SS + qt * 128 + w * 32 + lq) * DH + hi * 8;
    s16x8 qf[4];
    #pragma unroll
    for (int s5 = 0; s5 < 4; ++s5)
        qf[s5] = *reinterpret_cast<const s16x8*>(qp + s5 * 16);

    // staging: chunk u (16B) -> LDS chunk u ^ ((u>>3)&7); source stays linear/coalesced
    const int u0 = t, u1 = t + 256;
    const __hip_bfloat16* kb = k_ws + (size_t)pair * SS * DH;
    const __hip_bfloat16* vb = v_ws + (size_t)pair * DH * SS;
    const int ksw0 = (u0 ^ ((u0 >> 3) & 7)) * 16;
    const int ksw1 = (u1 ^ ((u1 >> 3) & 7)) * 16;
    const size_t voff0 = (size_t)(u0 >> 3) * SS + (u0 & 7) * 8;
    const size_t voff1 = (size_t)(u1 >> 3) * SS + (u1 & 7) * 8;

    s16x8 kr0 = *reinterpret_cast<const s16x8*>(kb + u0 * 8);
    s16x8 kr1 = *reinterpret_cast<const s16x8*>(kb + u1 * 8);
    s16x8 vr0 = *reinterpret_cast<const s16x8*>(vb + voff0);
    s16x8 vr1 = *reinterpret_cast<const s16x8*>(vb + voff1);

    f32x16 o0, o1;
    #pragma unroll
    for (int r = 0; r < 16; ++r) { o0[r] = 0.0f; o1[r] = 0.0f; }
    float m_run = -3.0e38f, lsum = 0.0f;
    const float cml = 0.18033688011112042f;  // log2(e)/8 : folds 1/sqrt(64) + exp2 domain

    const int kbase0 = lq * 128;
    const int kbase1 = (32 + lq) * 128;
    const int swz = (lq & 7) << 4;

    for (int kt = 0; kt < 16; ++kt) {
        __syncthreads();                           // prev tile fully consumed
        *reinterpret_cast<s16x8*>(Kl + ksw0) = kr0;
        *reinterpret_cast<s16x8*>(Kl + ksw1) = kr1;
        *reinterpret_cast<s16x8*>(Vl + ksw0) = vr0;
        *reinterpret_cast<s16x8*>(Vl + ksw1) = vr1;
        __syncthreads();
        if (kt < 15) {                             // T14: issue next-tile loads under compute
            kr0 = *reinterpret_cast<const s16x8*>(kb + (kt + 1) * 4096 + u0 * 8);
            kr1 = *reinterpret_cast<const s16x8*>(kb + (kt + 1) * 4096 + u1 * 8);
            vr0 = *reinterpret_cast<const s16x8*>(vb + voff0 + (kt + 1) * 64);
            vr1 = *reinterpret_cast<const s16x8*>(vb + voff1 + (kt + 1) * 64);
        }

        // QK^T (swapped): sc[g] = K_g . Q^T   (4 chained k=16 steps over d=64)
        f32x16 sc0, sc1;
        #pragma unroll
        for (int r = 0; r < 16; ++r) { sc0[r] = 0.0f; sc1[r] = 0.0f; }
        #pragma unroll
        for (int s5 = 0; s5 < 4; ++s5) {
            const int co = (2 * s5 + hi) << 4;
            s16x8 ka = *reinterpret_cast<const s16x8*>(Kl + kbase0 + (co ^ swz));
            sc0 = mfma32(ka, qf[s5], sc0);
        }
        #pragma unroll
        for (int s5 = 0; s5 < 4; ++s5) {
            const int co = (2 * s5 + hi) << 4;
            s16x8 ka = *reinterpret_cast<const s16x8*>(Kl + kbase1 + (co ^ swz));
            sc1 = mfma32(ka, qf[s5], sc1);
        }

        // online softmax, fully in-register (raw-score domain, exp2 with folded scale)
        float mx = fmaxf(sc0[0], sc1[0]);
        #pragma unroll
        for (int r = 1; r < 16; ++r) mx = fmaxf(mx, fmaxf(sc0[r], sc1[r]));
        mx = fmaxf(mx, __shfl_xor(mx, 32));
        if (!__all((mx - m_run) * cml <= 8.0f)) {  // T13 defer-rescale (P bounded by 2^8)
            float mnew  = fmaxf(m_run, mx);
            float alpha = fast_exp2((m_run - mnew) * cml);
            lsum *= alpha;
            #pragma unroll
            for (int r = 0; r < 16; ++r) { o0[r] *= alpha; o1[r] *= alpha; }
            m_run = mnew;
        }
        const float nm = -m_run * cml;
        float rs = 0.0f;
        #pragma unroll
        for (int r = 0; r < 16; ++r) {
            sc0[r] = fast_exp2(fmaf(sc0[r], cml, nm));
            sc1[r] = fast_exp2(fmaf(sc1[r], cml, nm));
            rs += sc0[r] + sc1[r];
        }
        rs += __shfl_xor(rs, 32);
        lsum += rs;

        // P -> A-frag via shfl_xor(32) half-exchange (defined semantics) + PV.
        // Desired per s5: word j=0,1 keys {16s5+8hi+0,1}; j=2,3: +2; j=4,5: +4; j=6,7: +6.
        #pragma unroll
        for (int s5 = 0; s5 < 4; ++s5) {
            const int sb8 = (s5 & 1) * 8;
            unsigned a0, b0, a1, b1;
            if (s5 < 2) {
                a0 = pk_bf16(sc0[sb8 + 0], sc0[sb8 + 1]);
                b0 = pk_bf16(sc0[sb8 + 4], sc0[sb8 + 5]);
                a1 = pk_bf16(sc0[sb8 + 2], sc0[sb8 + 3]);
                b1 = pk_bf16(sc0[sb8 + 6], sc0[sb8 + 7]);
            } else {
                a0 = pk_bf16(sc1[sb8 + 0], sc1[sb8 + 1]);
                b0 = pk_bf16(sc1[sb8 + 4], sc1[sb8 + 5]);
                a1 = pk_bf16(sc1[sb8 + 2], sc1[sb8 + 3]);
                b1 = pk_bf16(sc1[sb8 + 6], sc1[sb8 + 7]);
            }
            const unsigned sa0 = (unsigned)__shfl_xor((int)a0, 32);
            const unsigned sb0 = (unsigned)__shfl_xor((int)b0, 32);
            const unsigned sa1 = (unsigned)__shfl_xor((int)a1, 32);
            const unsigned sb1 = (unsigned)__shfl_xor((int)b1, 32);
            union { unsigned u[4]; s16x8 v; } af;
            af.u[0] = hi ? sb0 : a0;   // keys 16s5+8hi+{0,1}
            af.u[1] = hi ? sb1 : a1;   // keys 16s5+8hi+{2,3}
            af.u[2] = hi ? b0 : sa0;   // keys 16s5+8hi+{4,5}
            af.u[3] = hi ? b1 : sa1;   // keys 16s5+8hi+{6,7}
            const int co = (2 * s5 + hi) << 4;
            s16x8 vb0 = *reinterpret_cast<const s16x8*>(Vl + kbase0 + (co ^ swz));
            o0 = mfma32(af.v, vb0, o0);
            s16x8 vb1 = *reinterpret_cast<const s16x8*>(Vl + kbase1 + (co ^ swz));
            o1 = mfma32(af.v, vb1, o1);
        }
    }

    // epilogue: O / lsum ; PV C-layout row = (r&3)+8*(r>>2)+4*hi, col = d = lq (+32 for o1)
    const float inv = 1.0f / lsum;
    #pragma unroll
    for (int r = 0; r < 16; ++r) {
        const int qr = (r & 3) + 8 * (r >> 2) + 4 * hi;
        const float invr = __shfl(inv, qr);
        float* op = out + ((size_t)b * SS + qt * 128 + w * 32 + qr) * DM + h * DH + lq;
        op[0]  = o0[r] * invr;
        op[32] = o1[r] * invr;
    }
}

extern "C" void kernel_launch(void* const* d_in, const int* in_sizes, int n_in,
                              void* d_out, int out_size, void* d_ws, size_t ws_size,
                              hipStream_t stream) {
    const float* x  = (const float*)d_in[0];
    const float* Wq = (const float*)d_in[1];
    const float* Wk = (const float*)d_in[2];
    const float* Wv = (const float*)d_in[3];
    const float* bq = (const float*)d_in[4];
    const float* bv_ = (const float*)d_in[6];
    const float* bk = (const float*)d_in[5];
    float* out = (float*)d_out;

    __hip_bfloat16* q_ws = (__hip_bfloat16*)d_ws;
    __hip_bfloat16* k_ws = q_ws + (size_t)BB * HH * SS * DH;
    __hip_bfloat16* v_ws = k_ws + (size_t)BB * HH * SS * DH;

    qkv_proj_kernel<<<dim3(BB * HH * (SS / 128)), dim3(192), 0, stream>>>(
        x, Wq, Wk, Wv, bq, bk, bv_, q_ws, k_ws, v_ws);
    attn_kernel<<<dim3(BB * HH * (SS / 64 / 2)), dim3(256), 0, stream>>>(
        q_ws, k_ws, v_ws, out);
}

// Round 5
// 59.623 us; speedup vs baseline: 2.7299x; 1.5993x over previous
//
#include <hip/hip_runtime.h>
#include <hip/hip_bf16.h>

constexpr int BB = 4;
constexpr int SS = 1024;
constexpr int HH = 16;
constexpr int DH = 64;
constexpr int DM = 1024;

using f32x16 = __attribute__((ext_vector_type(16))) float;
using s16x8  = __attribute__((ext_vector_type(8))) short;

__device__ __forceinline__ f32x16 mfma32(s16x8 a, s16x8 b, f32x16 c) {
    return __builtin_amdgcn_mfma_f32_32x32x16_bf16(a, b, c, 0, 0, 0);
}

__device__ __forceinline__ unsigned short bf16bits(float x) {
    union { __hip_bfloat16 h; unsigned short s; } cv;
    cv.h = __float2bfloat16(x);
    return cv.s;
}
__device__ __forceinline__ unsigned pk_bf16(float lo, float hi) {
    return (unsigned)bf16bits(lo) | ((unsigned)bf16bits(hi) << 16);
}

__device__ __forceinline__ float fast_exp2(float x) {
#if __has_builtin(__builtin_amdgcn_exp2f)
    return __builtin_amdgcn_exp2f(x);
#else
    return __expf(x * 0.6931471805599453f);
#endif
}

// ---------------- QKV projection (MFMA) ----------------
// grid 512 = (B*H)*(S/128); block 256 = 4 waves; wave w owns s-rows [w*32, w*32+32).
// Y_m = X_tile[128x64] @ W_m^T + b_m  for m in {q,k,v}, via mfma_f32_32x32x16_bf16.
// A = X from swizzled LDS (same pattern as attn K-tile); B = W rows from global
// (W[e][d] IS W^T[d][e] fragment: lane=col e holds 8 contiguous d's).
// C layout (HW-verified): row = (r&3)+8*(r>>2)+4*hi, col = lq.
// V output transposed to [B,H,64,S] through swizzled LDS tile -> 16B coalesced stores.
__global__ __launch_bounds__(256) void qkv_proj_kernel(
    const float* __restrict__ x,
    const float* __restrict__ Wq, const float* __restrict__ Wk, const float* __restrict__ Wv,
    const float* __restrict__ bq, const float* __restrict__ bk, const float* __restrict__ bv,
    __hip_bfloat16* __restrict__ q_ws, __hip_bfloat16* __restrict__ k_ws,
    __hip_bfloat16* __restrict__ v_ws)
{
    const int bid  = blockIdx.x;
    const int tile = bid & 7;
    const int pair = bid >> 3;
    const int b = pair >> 4, h = pair & 15;
    const int t = threadIdx.x;
    const int w = t >> 6, l = t & 63;
    const int lq = l & 31, hi = l >> 5;
    const int s0 = tile * 128;

    __shared__ __align__(16) char Xs[16384];   // [128 s][128B], off ^= (row&7)<<4
    __shared__ __align__(16) char Vt[16384];   // [64 e][256B],  off ^= (row&7)<<4

    // stage X (fp32 -> bf16), 16B global loads, 8B swizzled LDS writes
    {
        const float* xb = x + (size_t)(b * SS + s0) * DM + h * DH;
        #pragma unroll
        for (int i = 0; i < 8; ++i) {
            const int c  = t + 256 * i;
            const int r  = c >> 4, cw = c & 15;
            float4 v4 = *reinterpret_cast<const float4*>(xb + (size_t)r * DM + cw * 4);
            uint2 p;
            p.x = pk_bf16(v4.x, v4.y);
            p.y = pk_bf16(v4.z, v4.w);
            *reinterpret_cast<uint2*>(Xs + r * 128 + ((cw * 8) ^ ((r & 7) << 4))) = p;
        }
    }
    __syncthreads();

    // A-fragments: X[w*32+lq][16s+8hi+0..7], reused for all 3 matrices
    const int arow = w * 32 + lq;
    const int asw  = (arow & 7) << 4;
    s16x8 af[4];
    #pragma unroll
    for (int s = 0; s < 4; ++s)
        af[s] = *reinterpret_cast<const s16x8*>(Xs + arow * 128 + ((s * 32 + hi * 16) ^ asw));

    #pragma unroll
    for (int m = 0; m < 3; ++m) {
        const float* Wm = (m == 0) ? Wq : (m == 1) ? Wk : Wv;
        const float* bm = (m == 0) ? bq : (m == 1) ? bk : bv;

        f32x16 a0, a1;
        #pragma unroll
        for (int r = 0; r < 16; ++r) { a0[r] = 0.0f; a1[r] = 0.0f; }

        #pragma unroll
        for (int s = 0; s < 4; ++s) {
            // B-frag: B[k=16s+8hi+j][col=e] = W[e][16s+8hi+j]; e = lq (half 0), 32+lq (half 1)
            const float* wp0 = Wm + (size_t)(h * DH + lq) * DH + s * 16 + hi * 8;
            const float* wp1 = wp0 + 32 * DH;
            float4 wa0 = reinterpret_cast<const float4*>(wp0)[0];
            float4 wb0 = reinterpret_cast<const float4*>(wp0)[1];
            float4 wa1 = reinterpret_cast<const float4*>(wp1)[0];
            float4 wb1 = reinterpret_cast<const float4*>(wp1)[1];
            union { unsigned u[4]; s16x8 v; } bf0, bf1;
            bf0.u[0] = pk_bf16(wa0.x, wa0.y); bf0.u[1] = pk_bf16(wa0.z, wa0.w);
            bf0.u[2] = pk_bf16(wb0.x, wb0.y); bf0.u[3] = pk_bf16(wb0.z, wb0.w);
            bf1.u[0] = pk_bf16(wa1.x, wa1.y); bf1.u[1] = pk_bf16(wa1.z, wa1.w);
            bf1.u[2] = pk_bf16(wb1.x, wb1.y); bf1.u[3] = pk_bf16(wb1.z, wb1.w);
            a0 = mfma32(af[s], bf0.v, a0);
            a1 = mfma32(af[s], bf1.v, a1);
        }

        const float bias0 = bm[h * DH + lq];
        const float bias1 = bm[h * DH + 32 + lq];

        if (m < 2) {
            __hip_bfloat16* dst = (m == 0) ? q_ws : k_ws;
            #pragma unroll
            for (int r = 0; r < 16; ++r) {
                const int qr = (r & 3) + 8 * (r >> 2) + 4 * hi;
                __hip_bfloat16* op = dst + ((size_t)pair * SS + s0 + w * 32 + qr) * DH;
                op[lq]      = __float2bfloat16(a0[r] + bias0);
                op[32 + lq] = __float2bfloat16(a1[r] + bias1);
            }
        } else {
            // Vt[e][s]: regs 4g..4g+3 are s-rows w*32 + 8g + 4hi + 0..3 (contiguous) -> 8B packs
            #pragma unroll
            for (int g = 0; g < 4; ++g) {
                const int off = w * 64 + g * 16 + hi * 8;
                uint2 p0, p1;
                p0.x = pk_bf16(a0[4*g+0] + bias0, a0[4*g+1] + bias0);
                p0.y = pk_bf16(a0[4*g+2] + bias0, a0[4*g+3] + bias0);
                p1.x = pk_bf16(a1[4*g+0] + bias1, a1[4*g+1] + bias1);
                p1.y = pk_bf16(a1[4*g+2] + bias1, a1[4*g+3] + bias1);
                *reinterpret_cast<uint2*>(Vt + lq * 256 + (off ^ ((lq & 7) << 4))) = p0;
                *reinterpret_cast<uint2*>(Vt + (32 + lq) * 256 + (off ^ (((32 + lq) & 7) << 4))) = p1;
            }
        }
    }
    __syncthreads();

    // Vt -> v_ws[pair][e][s0..s0+128), 16B coalesced stores
    #pragma unroll
    for (int i = 0; i < 4; ++i) {
        const int c   = t + 256 * i;
        const int row = c >> 4, cc = c & 15;
        s16x8 val = *reinterpret_cast<const s16x8*>(
            Vt + row * 256 + ((cc * 16) ^ ((row & 7) << 4)));
        *reinterpret_cast<s16x8*>(v_ws + ((size_t)pair * DH + row) * SS + s0 + cc * 8) = val;
    }
}

// ---------------- Flash attention (32x32 swapped-QK^T, in-register softmax) ----------------
// grid 512 = 64 pairs x 8 q-tiles (XCD-swizzled); block 256 = 4 waves x 32 q-rows.
// Swapped QK^T: sc = mfma(A=K, B=Q^T) -> C col = lane&31 = QUERY; lane holds 32 key-scores
// for its query: key(r,hi) = (r&3)+8*(r>>2)+4*hi (+32 per group).
// P half-exchange done with __shfl_xor(.,32)+select (semantics-safe).
// K/V LDS tiles [64][64] bf16 row-major, byte ^= (row&7)<<4 swizzle.
__global__ __launch_bounds__(256) void attn_kernel(
    const __hip_bfloat16* __restrict__ q_ws,
    const __hip_bfloat16* __restrict__ k_ws,
    const __hip_bfloat16* __restrict__ v_ws,
    float* __restrict__ out)
{
    const int bid  = blockIdx.x;
    const int lbid = (bid & 7) * 64 + (bid >> 3);   // XCD-aware swizzle (512 % 8 == 0)
    const int qt   = lbid & 7;
    const int pair = lbid >> 3;
    const int b = pair >> 4, h = pair & 15;
    const int t = threadIdx.x;
    const int w = t >> 6, l = t & 63;
    const int lq = l & 31, hi = l >> 5;

    __shared__ __align__(16) char Kl[8192];
    __shared__ __align__(16) char Vl[8192];

    // Q fragments (B-operand): lane holds Q[q=lq][16*s5 + 8*hi + 0..7]
    const __hip_bfloat16* qp = q_ws + ((size_t)pair * SS + qt * 128 + w * 32 + lq) * DH + hi * 8;
    s16x8 qf[4];
    #pragma unroll
    for (int s5 = 0; s5 < 4; ++s5)
        qf[s5] = *reinterpret_cast<const s16x8*>(qp + s5 * 16);

    // staging: chunk u (16B) -> LDS chunk u ^ ((u>>3)&7); source stays linear/coalesced
    const int u0 = t, u1 = t + 256;
    const __hip_bfloat16* kb = k_ws + (size_t)pair * SS * DH;
    const __hip_bfloat16* vb = v_ws + (size_t)pair * DH * SS;
    const int ksw0 = (u0 ^ ((u0 >> 3) & 7)) * 16;
    const int ksw1 = (u1 ^ ((u1 >> 3) & 7)) * 16;
    const size_t voff0 = (size_t)(u0 >> 3) * SS + (u0 & 7) * 8;
    const size_t voff1 = (size_t)(u1 >> 3) * SS + (u1 & 7) * 8;

    s16x8 kr0 = *reinterpret_cast<const s16x8*>(kb + u0 * 8);
    s16x8 kr1 = *reinterpret_cast<const s16x8*>(kb + u1 * 8);
    s16x8 vr0 = *reinterpret_cast<const s16x8*>(vb + voff0);
    s16x8 vr1 = *reinterpret_cast<const s16x8*>(vb + voff1);

    f32x16 o0, o1;
    #pragma unroll
    for (int r = 0; r < 16; ++r) { o0[r] = 0.0f; o1[r] = 0.0f; }
    float m_run = -3.0e38f, lsum = 0.0f;
    const float cml = 0.18033688011112042f;  // log2(e)/8 : folds 1/sqrt(64) + exp2 domain

    const int kbase0 = lq * 128;
    const int kbase1 = (32 + lq) * 128;
    const int swz = (lq & 7) << 4;

    for (int kt = 0; kt < 16; ++kt) {
        __syncthreads();                           // prev tile fully consumed
        *reinterpret_cast<s16x8*>(Kl + ksw0) = kr0;
        *reinterpret_cast<s16x8*>(Kl + ksw1) = kr1;
        *reinterpret_cast<s16x8*>(Vl + ksw0) = vr0;
        *reinterpret_cast<s16x8*>(Vl + ksw1) = vr1;
        __syncthreads();
        if (kt < 15) {                             // T14: issue next-tile loads under compute
            kr0 = *reinterpret_cast<const s16x8*>(kb + (kt + 1) * 4096 + u0 * 8);
            kr1 = *reinterpret_cast<const s16x8*>(kb + (kt + 1) * 4096 + u1 * 8);
            vr0 = *reinterpret_cast<const s16x8*>(vb + voff0 + (kt + 1) * 64);
            vr1 = *reinterpret_cast<const s16x8*>(vb + voff1 + (kt + 1) * 64);
        }

        // QK^T (swapped): sc[g] = K_g . Q^T   (4 chained k=16 steps over d=64)
        f32x16 sc0, sc1;
        #pragma unroll
        for (int r = 0; r < 16; ++r) { sc0[r] = 0.0f; sc1[r] = 0.0f; }
        #pragma unroll
        for (int s5 = 0; s5 < 4; ++s5) {
            const int co = (2 * s5 + hi) << 4;
            s16x8 ka = *reinterpret_cast<const s16x8*>(Kl + kbase0 + (co ^ swz));
            sc0 = mfma32(ka, qf[s5], sc0);
        }
        #pragma unroll
        for (int s5 = 0; s5 < 4; ++s5) {
            const int co = (2 * s5 + hi) << 4;
            s16x8 ka = *reinterpret_cast<const s16x8*>(Kl + kbase1 + (co ^ swz));
            sc1 = mfma32(ka, qf[s5], sc1);
        }

        // online softmax, fully in-register (raw-score domain, exp2 with folded scale)
        float mx = fmaxf(sc0[0], sc1[0]);
        #pragma unroll
        for (int r = 1; r < 16; ++r) mx = fmaxf(mx, fmaxf(sc0[r], sc1[r]));
        mx = fmaxf(mx, __shfl_xor(mx, 32));
        if (!__all((mx - m_run) * cml <= 8.0f)) {  // T13 defer-rescale (P bounded by 2^8)
            float mnew  = fmaxf(m_run, mx);
            float alpha = fast_exp2((m_run - mnew) * cml);
            lsum *= alpha;
            #pragma unroll
            for (int r = 0; r < 16; ++r) { o0[r] *= alpha; o1[r] *= alpha; }
            m_run = mnew;
        }
        const float nm = -m_run * cml;
        float rs = 0.0f;
        #pragma unroll
        for (int r = 0; r < 16; ++r) {
            sc0[r] = fast_exp2(fmaf(sc0[r], cml, nm));
            sc1[r] = fast_exp2(fmaf(sc1[r], cml, nm));
            rs += sc0[r] + sc1[r];
        }
        rs += __shfl_xor(rs, 32);
        lsum += rs;

        // P -> A-frag via shfl_xor(32) half-exchange (defined semantics) + PV.
        #pragma unroll
        for (int s5 = 0; s5 < 4; ++s5) {
            const int sb8 = (s5 & 1) * 8;
            unsigned a0, b0, a1, b1;
            if (s5 < 2) {
                a0 = pk_bf16(sc0[sb8 + 0], sc0[sb8 + 1]);
                b0 = pk_bf16(sc0[sb8 + 4], sc0[sb8 + 5]);
                a1 = pk_bf16(sc0[sb8 + 2], sc0[sb8 + 3]);
                b1 = pk_bf16(sc0[sb8 + 6], sc0[sb8 + 7]);
            } else {
                a0 = pk_bf16(sc1[sb8 + 0], sc1[sb8 + 1]);
                b0 = pk_bf16(sc1[sb8 + 4], sc1[sb8 + 5]);
                a1 = pk_bf16(sc1[sb8 + 2], sc1[sb8 + 3]);
                b1 = pk_bf16(sc1[sb8 + 6], sc1[sb8 + 7]);
            }
            const unsigned sa0 = (unsigned)__shfl_xor((int)a0, 32);
            const unsigned sb0 = (unsigned)__shfl_xor((int)b0, 32);
            const unsigned sa1 = (unsigned)__shfl_xor((int)a1, 32);
            const unsigned sb1 = (unsigned)__shfl_xor((int)b1, 32);
            union { unsigned u[4]; s16x8 v; } afr;
            afr.u[0] = hi ? sb0 : a0;   // keys 16s5+8hi+{0,1}
            afr.u[1] = hi ? sb1 : a1;   // keys 16s5+8hi+{2,3}
            afr.u[2] = hi ? b0 : sa0;   // keys 16s5+8hi+{4,5}
            afr.u[3] = hi ? b1 : sa1;   // keys 16s5+8hi+{6,7}
            const int co = (2 * s5 + hi) << 4;
            s16x8 vb0 = *reinterpret_cast<const s16x8*>(Vl + kbase0 + (co ^ swz));
            o0 = mfma32(afr.v, vb0, o0);
            s16x8 vb1 = *reinterpret_cast<const s16x8*>(Vl + kbase1 + (co ^ swz));
            o1 = mfma32(afr.v, vb1, o1);
        }
    }

    // epilogue: O / lsum ; PV C-layout row = (r&3)+8*(r>>2)+4*hi, col = d = lq (+32 for o1)
    const float inv = 1.0f / lsum;
    #pragma unroll
    for (int r = 0; r < 16; ++r) {
        const int qr = (r & 3) + 8 * (r >> 2) + 4 * hi;
        const float invr = __shfl(inv, qr);
        float* op = out + ((size_t)b * SS + qt * 128 + w * 32 + qr) * DM + h * DH + lq;
        op[0]  = o0[r] * invr;
        op[32] = o1[r] * invr;
    }
}

extern "C" void kernel_launch(void* const* d_in, const int* in_sizes, int n_in,
                              void* d_out, int out_size, void* d_ws, size_t ws_size,
                              hipStream_t stream) {
    const float* x  = (const float*)d_in[0];
    const float* Wq = (const float*)d_in[1];
    const float* Wk = (const float*)d_in[2];
    const float* Wv = (const float*)d_in[3];
    const float* bq = (const float*)d_in[4];
    const float* bk = (const float*)d_in[5];
    const float* bv = (const float*)d_in[6];
    float* out = (float*)d_out;

    __hip_bfloat16* q_ws = (__hip_bfloat16*)d_ws;
    __hip_bfloat16* k_ws = q_ws + (size_t)BB * HH * SS * DH;
    __hip_bfloat16* v_ws = k_ws + (size_t)BB * HH * SS * DH;

    qkv_proj_kernel<<<dim3(BB * HH * (SS / 128)), dim3(256), 0, stream>>>(
        x, Wq, Wk, Wv, bq, bk, bv, q_ws, k_ws, v_ws);
    attn_kernel<<<dim3(BB * HH * (SS / 64 / 2)), dim3(256), 0, stream>>>(
        q_ws, k_ws, v_ws, out);
}